// Round 5
// baseline (320.813 us; speedup 1.0000x reference)
//
#include <hip/hip_runtime.h>
#include <math.h>

// Problem dims: B=4, T=128, I=32, H=64 (compile-time)
// d_out float layout (reference return order):
// final_carry (4,64) | out (4,128,64) | J_Wi (4,128,64,32,64) | J_Wh (4,128,64,64,64)
// | J_b (4,128,64,64) | J_h (4,128,64,4,64)
#define OFF_OUT   256u
#define OFF_JWI   33024u
#define OFF_JWH   67141888u
#define OFF_JB    201359616u
#define OFF_JH    203456768u
#define OUT_TOTAL 211845376u

typedef float f32x4 __attribute__((ext_vector_type(4)));

static __device__ __forceinline__ float tanh_fast(float x) {
    // tanh(x) = 1 - 2/(e^{2x}+1); exact limits, ~1e-6 rel error
    float t = __expf(2.0f * x);
    return 1.0f - 2.0f / (t + 1.0f);
}

// ---------------------------------------------------------------------------
// Kernel 1: u[bt,j] = b[j] + sum_i x[bt,i]*Wi[i,j], staged INTO the `out`
// region (scan consumes it in place: u[t+1] is read before slot t is
// overwritten by a). 128 blocks x 256 threads.
// ---------------------------------------------------------------------------
__global__ __launch_bounds__(256) void xwi_kernel(
    const float* __restrict__ x, const float* __restrict__ Wi,
    const float* __restrict__ bias, float* __restrict__ out)
{
    const int tid = threadIdx.x;
    const int row = blockIdx.x * 4 + (tid >> 6);   // bt in [0,512)
    const int j = tid & 63;
    const float* xr = x + row * 32;
    float acc = bias[j];
#pragma unroll
    for (int i = 0; i < 32; ++i) acc = fmaf(xr[i], Wi[i * 64 + j], acc);
    out[OFF_OUT + row * 64 + j] = acc;
}

// ---------------------------------------------------------------------------
// Kernel 2: block 0 = sequential scan (wave w = batch w, barrier-free; u is
// read from and `a` written back to the same out-region slots).
// Blocks 1..G-1 = pure linear memset of the ENTIRE Jacobian span
// [OFF_JWI, OUT_TOTAL) — full 256B lines, sequential, NT stores.
// ---------------------------------------------------------------------------
__global__ __launch_bounds__(256) void scan_zero_kernel(
    const float* __restrict__ carry, const float* __restrict__ Wh,
    float* __restrict__ out)
{
    const int tid = threadIdx.x;
    if (blockIdx.x == 0) {
        const int w = tid >> 6, j = tid & 63;
        float wcol[64];
#pragma unroll
        for (int m = 0; m < 64; ++m) wcol[m] = Wh[m * 64 + j];
        __shared__ __align__(16) float sh[256];
        sh[tid] = carry[tid];
        float* ub = out + OFF_OUT + w * 8192;   // u in, a out (in place)
        const f32x4* shv = reinterpret_cast<const f32x4*>(sh + w * 64);
        float unext = ub[j];
        float a = 0.0f;
        for (int t = 0; t < 128; ++t) {
            const float pre = unext;
            if (t < 127) unext = ub[(t + 1) * 64 + j];
            float a0 = 0.f, a1 = 0.f, a2 = 0.f, a3 = 0.f;
#pragma unroll
            for (int mm = 0; mm < 16; ++mm) {
                const f32x4 hv = shv[mm];        // lane-uniform 16B read
                a0 = fmaf(hv.x, wcol[mm * 4 + 0], a0);
                a1 = fmaf(hv.y, wcol[mm * 4 + 1], a1);
                a2 = fmaf(hv.z, wcol[mm * 4 + 2], a2);
                a3 = fmaf(hv.w, wcol[mm * 4 + 3], a3);
            }
            a = tanh_fast(pre + (a0 + a1) + (a2 + a3));
            ub[t * 64 + j] = a;
            sh[tid] = a;                         // next iter reads it
        }
        out[tid] = a;                            // final carry
    } else {
        const unsigned startv = OFF_JWI >> 2;    // f32x4-aligned (8256)
        const unsigned endv   = OUT_TOTAL >> 2;
        const unsigned stride = (gridDim.x - 1u) * 256u;
        const f32x4 z = {0.f, 0.f, 0.f, 0.f};
        f32x4* o4 = reinterpret_cast<f32x4*>(out);
        for (unsigned v = startv + (blockIdx.x - 1u) * 256u + tid;
             v < endv; v += stride)
            __builtin_nontemporal_store(z, o4 + v);
    }
}

// ---------------------------------------------------------------------------
// Kernel 3: nonzero payload only (everything else is already zero).
// Wave-tasks (branches wave-uniform):
//   w <  32768: J_Wh diag — task=(bt,j), lane=m, one 16B store each
//   w <  49152: J_Wi diag — task=2 pairs (bt,j), lane%32=i
//   w <  49664: J_b diag  — task=64 rows, lane=row, one 16B store
//   w <  57856: J_h dense — task=4 rows (c==b slice), 16 lanes/row
// ---------------------------------------------------------------------------
__global__ __launch_bounds__(256) void diag_fill_kernel(
    const float* __restrict__ carry, const float* __restrict__ x,
    const float* __restrict__ Wh, float* __restrict__ out)
{
    const int tid = threadIdx.x;
    const unsigned nW = gridDim.x * 4u;
    const unsigned l = tid & 63u;
    const float* __restrict__ outh = out + OFF_OUT;

    for (unsigned w = blockIdx.x * 4u + (tid >> 6); w < 57856u; w += nW) {
        unsigned addr;
        f32x4 r;
        if (w < 32768u) {
            // J_Wh: row = (bt*64+j)*64 + m = w*64 + l
            const unsigned bt = w >> 6, j = w & 63u;
            const unsigned t = bt & 127u, b = bt >> 7;
            const float a = outh[bt * 64u + j];
            const float g = 1.0f - a * a;
            const float hv = (t == 0u) ? carry[b * 64u + l]
                                       : outh[(bt - 1u) * 64u + l];
            const float v = g * hv;
            const unsigned d = j & 3u;
            r.x = (d == 0u) ? v : 0.f; r.y = (d == 1u) ? v : 0.f;
            r.z = (d == 2u) ? v : 0.f; r.w = (d == 3u) ? v : 0.f;
            addr = OFF_JWH + w * 4096u + l * 64u + (j & ~3u);
        } else if (w < 49152u) {
            // J_Wi: two (bt,j) pairs per wave, lane%32 = i
            const unsigned pair = (w - 32768u) * 2u + (l >> 5);
            const unsigned bt = pair >> 6, j = pair & 63u;
            const float a = outh[bt * 64u + j];
            const float g = 1.0f - a * a;
            const unsigned i = l & 31u;
            const float v = g * x[bt * 32u + i];
            const unsigned d = j & 3u;
            r.x = (d == 0u) ? v : 0.f; r.y = (d == 1u) ? v : 0.f;
            r.z = (d == 2u) ? v : 0.f; r.w = (d == 3u) ? v : 0.f;
            addr = OFF_JWI + (pair * 32u + i) * 64u + (j & ~3u);
        } else if (w < 49664u) {
            // J_b: row p = bt*64+j, one diag float4 per row
            const unsigned p = (w - 49152u) * 64u + l;
            const unsigned j = p & 63u;
            const float a = outh[p];
            const float g = 1.0f - a * a;
            const unsigned d = j & 3u;
            r.x = (d == 0u) ? g : 0.f; r.y = (d == 1u) ? g : 0.f;
            r.z = (d == 2u) ? g : 0.f; r.w = (d == 3u) ? g : 0.f;
            addr = OFF_JB + p * 64u + (j & ~3u);
        } else {
            // J_h dense c==b rows: 4 rows/wave, 16 lanes per 64-float row
            const unsigned p = (w - 49664u) * 4u + (l >> 4);  // bt*64+j
            const unsigned bt = p >> 6, j = p & 63u, b = bt >> 7;
            const float a = outh[p];
            const float g = 1.0f - a * a;
            const unsigned m0 = (l & 15u) * 4u;
            r.x = g * Wh[(m0 + 0u) * 64u + j];
            r.y = g * Wh[(m0 + 1u) * 64u + j];
            r.z = g * Wh[(m0 + 2u) * 64u + j];
            r.w = g * Wh[(m0 + 3u) * 64u + j];
            addr = OFF_JH + p * 256u + b * 64u + m0;
        }
        __builtin_nontemporal_store(r, reinterpret_cast<f32x4*>(out + addr));
    }
}

extern "C" void kernel_launch(void* const* d_in, const int* in_sizes, int n_in,
                              void* d_out, int out_size, void* d_ws, size_t ws_size,
                              hipStream_t stream) {
    const float* carry = (const float*)d_in[0];
    const float* x     = (const float*)d_in[1];
    const float* Wi    = (const float*)d_in[2];
    const float* Wh    = (const float*)d_in[3];
    const float* bias  = (const float*)d_in[4];
    float* out = (float*)d_out;

    xwi_kernel      <<<128, 256, 0, stream>>>(x, Wi, bias, out);
    scan_zero_kernel<<<2048, 256, 0, stream>>>(carry, Wh, out);
    diag_fill_kernel<<<2048, 256, 0, stream>>>(carry, x, Wh, out);
}

// Round 6
// 203.678 us; speedup vs baseline: 1.5751x; 1.5751x over previous
//
#include <hip/hip_runtime.h>
#include <math.h>

// Problem dims: B=4, T=128, I=32, H=64 (compile-time)
// d_out float layout (reference return order):
// final_carry (4,64) | out (4,128,64) | J_Wi (4,128,64,32,64) | J_Wh (4,128,64,64,64)
// | J_b (4,128,64,64) | J_h (4,128,64,4,64)
#define OFF_OUT   256u
#define OFF_JWI   33024u
#define OFF_JWH   67141888u
#define OFF_JB    201359616u
#define OFF_JH    203456768u
#define OUT_TOTAL 211845376u

typedef float f32x4 __attribute__((ext_vector_type(4)));

static __device__ __forceinline__ float tanh_fast(float x) {
    // tanh(x) = 1 - 2/(e^{2x}+1); exact limits, ~1e-6 rel error
    float t = __expf(2.0f * x);
    return 1.0f - 2.0f / (t + 1.0f);
}

// ---------------------------------------------------------------------------
// Kernel 1: u[bt,j] = b[j] + sum_i x[bt,i]*Wi[i,j], staged INTO the `out`
// region (scan consumes it and overwrites with a). 128 blocks x 256 threads.
// ---------------------------------------------------------------------------
__global__ __launch_bounds__(256) void xwi_kernel(
    const float* __restrict__ x, const float* __restrict__ Wi,
    const float* __restrict__ bias, float* __restrict__ out)
{
    const int tid = threadIdx.x;
    const int row = blockIdx.x * 4 + (tid >> 6);   // bt in [0,512)
    const int j = tid & 63;
    const float* xr = x + row * 32;
    float acc = bias[j];
#pragma unroll
    for (int i = 0; i < 32; ++i) acc = fmaf(xr[i], Wi[i * 64 + j], acc);
    out[OFF_OUT + row * 64 + j] = acc;
}

// ---------------------------------------------------------------------------
// Kernel 2: sequential scan. 4 blocks (1 wave each), block = batch.
// u preloaded into LDS (no global-latency on the critical path);
// Wh column j in 64 VGPRs; h exchange via same-wave LDS (no barriers).
// ---------------------------------------------------------------------------
__global__ __launch_bounds__(64) void scan_kernel(
    const float* __restrict__ carry, const float* __restrict__ Wh,
    float* __restrict__ out)
{
    const int b = blockIdx.x;
    const int j = threadIdx.x;
    __shared__ __align__(16) float uL[128 * 64];   // 32 KB
    __shared__ __align__(16) float sh[64];

    float wcol[64];
#pragma unroll
    for (int m = 0; m < 64; ++m) wcol[m] = Wh[m * 64 + j];

    float* ub = out + OFF_OUT + b * 8192;          // u in, a out (in place)
#pragma unroll 4
    for (int p = j; p < 8192; p += 64) uL[p] = ub[p];
    sh[j] = carry[b * 64 + j];

    const f32x4* shv = reinterpret_cast<const f32x4*>(sh);
    float a = 0.0f;
    for (int t = 0; t < 128; ++t) {
        const float pre = uL[t * 64 + j];
        float a0 = 0.f, a1 = 0.f, a2 = 0.f, a3 = 0.f;
#pragma unroll
        for (int mm = 0; mm < 16; ++mm) {
            const f32x4 hv = shv[mm];              // lane-uniform broadcast
            a0 = fmaf(hv.x, wcol[mm * 4 + 0], a0);
            a1 = fmaf(hv.y, wcol[mm * 4 + 1], a1);
            a2 = fmaf(hv.z, wcol[mm * 4 + 2], a2);
            a3 = fmaf(hv.w, wcol[mm * 4 + 3], a3);
        }
        a = tanh_fast(pre + (a0 + a1) + (a2 + a3));
        ub[t * 64 + j] = a;                        // fire-and-forget store
        sh[j] = a;                                 // next iter reads (same wave)
    }
    out[b * 64 + j] = a;                           // final carry
}

// ---------------------------------------------------------------------------
// Kernel 3: dense single-touch fill of ALL Jacobians. Full 256B lines,
// block-contiguous chunks, LDS-staged reads, NT stores.
//   blk [0,2048):     J_Wh  (idx: bt = idx>>2, j-quarter = idx&3) 256KB each
//   blk [2048,3072):  J_Wi  (idx: bt = idx>>1, j-half = idx&1)    256KB each
//   blk [3072,3104):  J_b   (c: rows [c*1024, +1024))             256KB each
//   blk [3104,3232):  J_h   (q: 4 bt-slabs each)                  64KB each
// ---------------------------------------------------------------------------
__global__ __launch_bounds__(256) void fill_kernel(
    const float* __restrict__ carry, const float* __restrict__ x,
    const float* __restrict__ Wh, float* __restrict__ out)
{
    __shared__ float smem[4608];                   // 18 KB (J_h: whT+sg)
    const int tid = threadIdx.x;
    const unsigned blk = blockIdx.x;
    const float* __restrict__ outh = out + OFF_OUT;
    const unsigned rowq = tid >> 4;                // 16-lane group id [0,16)
    const unsigned k0 = (tid & 15u) * 4;           // k offset of lane's float4

    if (blk < 2048u) {
        // ---- J_Wh ----
        const unsigned bt = blk >> 2, jq = blk & 3u;
        const unsigned t = bt & 127u, bb = bt >> 7;
        if (tid < 16) {
            const float aa = outh[bt * 64 + jq * 16 + tid];
            smem[tid] = 1.0f - aa * aa;            // g[jloc]
        } else if (tid >= 64 && tid < 128) {
            const unsigned m = tid - 64;
            smem[64 + m] = (t == 0u) ? carry[bb * 64 + m]
                                     : outh[(bt - 1u) * 64 + m];
        }
        __syncthreads();
        f32x4* dst = reinterpret_cast<f32x4*>(
            out + (size_t)OFF_JWH + (size_t)bt * 262144 + jq * 65536);
        const unsigned jbase = jq * 16;
#pragma unroll 2
        for (int it = 0; it < 64; ++it) {
            const unsigned R = it * 16 + rowq;     // (jloc,m) row in [0,1024)
            const unsigned jloc = R >> 6, m = R & 63u;
            const float val = smem[jloc] * smem[64 + m];
            const unsigned d = (jbase + jloc) - k0;
            f32x4 r;
            r.x = (d == 0u) ? val : 0.f; r.y = (d == 1u) ? val : 0.f;
            r.z = (d == 2u) ? val : 0.f; r.w = (d == 3u) ? val : 0.f;
            __builtin_nontemporal_store(r, dst + it * 256 + tid);
        }
    } else if (blk < 3072u) {
        // ---- J_Wi ----
        const unsigned idx = blk - 2048u;
        const unsigned bt = idx >> 1, jh = idx & 1u;
        if (tid < 32) {
            const float aa = outh[bt * 64 + jh * 32 + tid];
            smem[tid] = 1.0f - aa * aa;            // g[jloc]
            smem[32 + tid] = x[bt * 32 + tid];     // x[i]
        }
        __syncthreads();
        f32x4* dst = reinterpret_cast<f32x4*>(
            out + (size_t)OFF_JWI + (size_t)bt * 131072 + jh * 65536);
        const unsigned jbase = jh * 32;
#pragma unroll 2
        for (int it = 0; it < 64; ++it) {
            const unsigned R = it * 16 + rowq;     // (jloc,i) row in [0,1024)
            const unsigned jloc = R >> 5, i = R & 31u;
            const float val = smem[jloc] * smem[32 + i];
            const unsigned d = (jbase + jloc) - k0;
            f32x4 r;
            r.x = (d == 0u) ? val : 0.f; r.y = (d == 1u) ? val : 0.f;
            r.z = (d == 2u) ? val : 0.f; r.w = (d == 3u) ? val : 0.f;
            __builtin_nontemporal_store(r, dst + it * 256 + tid);
        }
    } else if (blk < 3104u) {
        // ---- J_b ----
        const unsigned c = blk - 3072u;
        for (int p = tid; p < 1024; p += 256) {
            const float aa = outh[c * 1024 + p];
            smem[p] = 1.0f - aa * aa;
        }
        __syncthreads();
        f32x4* dst = reinterpret_cast<f32x4*>(
            out + (size_t)OFF_JB + (size_t)c * 65536);
#pragma unroll 2
        for (int it = 0; it < 64; ++it) {
            const unsigned R = it * 16 + rowq;     // local row
            const unsigned j = R & 63u;
            const float val = smem[R];
            const unsigned d = j - k0;
            f32x4 r;
            r.x = (d == 0u) ? val : 0.f; r.y = (d == 1u) ? val : 0.f;
            r.z = (d == 2u) ? val : 0.f; r.w = (d == 3u) ? val : 0.f;
            __builtin_nontemporal_store(r, dst + it * 256 + tid);
        }
    } else {
        // ---- J_h ---- (whT stride 68: 16B-aligned rows, low bank aliasing)
        const unsigned q = blk - 3104u;            // [0,128): 4 bt-slabs each
        float* whT = smem;                         // 64*68 floats
        float* sg = smem + 4352;                   // 256 floats
        for (int p = tid; p < 4096; p += 256) {
            const unsigned m = p >> 6, j = p & 63u;
            whT[j * 68 + m] = Wh[p];
        }
        {
            const unsigned s = tid >> 6, j = tid & 63u;
            const float aa = outh[(q * 4 + s) * 64 + j];
            sg[tid] = 1.0f - aa * aa;
        }
        __syncthreads();
        const unsigned m0 = (tid & 15u) * 4;
        f32x4* dst = reinterpret_cast<f32x4*>(
            out + (size_t)OFF_JH + (size_t)q * 65536);
#pragma unroll 2
        for (int it = 0; it < 64; ++it) {
            const unsigned R = it * 16 + rowq;     // row = s*256 + j*4 + c
            const unsigned s = R >> 8;
            const unsigned j = (R >> 2) & 63u;
            const unsigned cc = R & 3u;
            const unsigned bb = (q * 4 + s) >> 7;
            f32x4 r = {0.f, 0.f, 0.f, 0.f};
            if (cc == bb) {
                const float g = sg[s * 64 + j];
                const float* wrow = &whT[j * 68 + m0];
                r.x = g * wrow[0]; r.y = g * wrow[1];
                r.z = g * wrow[2]; r.w = g * wrow[3];
            }
            __builtin_nontemporal_store(r, dst + it * 256 + tid);
        }
    }
}

extern "C" void kernel_launch(void* const* d_in, const int* in_sizes, int n_in,
                              void* d_out, int out_size, void* d_ws, size_t ws_size,
                              hipStream_t stream) {
    const float* carry = (const float*)d_in[0];
    const float* x     = (const float*)d_in[1];
    const float* Wi    = (const float*)d_in[2];
    const float* Wh    = (const float*)d_in[3];
    const float* bias  = (const float*)d_in[4];
    float* out = (float*)d_out;

    xwi_kernel <<<128, 256, 0, stream>>>(x, Wi, bias, out);
    scan_kernel<<<4, 64, 0, stream>>>(carry, Wh, out);
    fill_kernel<<<3232, 256, 0, stream>>>(carry, x, Wh, out);
}